// Round 1
// baseline (2875.315 us; speedup 1.0000x reference)
//
#include <hip/hip_runtime.h>
#include <math.h>

#define PI_F 3.14159265358979323846f

constexpr int E = 512;   // feature dim
constexpr int Q = 64;    // quantum dim
constexpr int MTILE = 64;  // rows per block
constexpr int BK = 16;     // K chunk
constexpr int RPT = 16;    // rows per thread (per wave: 64 lanes x 16 rows)

__global__ __launch_bounds__(256)
void qi_fused(const float* __restrict__ feat,
              const float* __restrict__ Wr,  const float* __restrict__ br,
              const float* __restrict__ Wi,  const float* __restrict__ bi,
              const float* __restrict__ Wp1, const float* __restrict__ bp1,
              const float* __restrict__ Wp2, const float* __restrict__ bp2,
              const float* __restrict__ op_p,
              float* __restrict__ out, long long nrows)
{
    __shared__ float A[MTILE][BK];     // 4 KB   feature chunk
    __shared__ float T[MTILE][Q + 4];  // 17 KB  tanh(p1) staging (stride 68 floats = 16B aligned)

    const int tid = threadIdx.x;
    const int j   = tid & 63;          // output column (lane)
    const int w   = tid >> 6;          // wave id -> row group
    const long long row0 = (long long)blockIdx.x * MTILE;

    float accR[RPT], accI[RPT], accP[RPT];
    #pragma unroll
    for (int r = 0; r < RPT; ++r) { accR[r] = 0.f; accI[r] = 0.f; accP[r] = 0.f; }

    // A-tile loader mapping: thread t loads float4 at (row = t/4, k = (t%4)*4)
    const int lrow = tid >> 2;
    const int lk   = (tid & 3) << 2;
    const float* featp = feat + (row0 + lrow) * (long long)E + lk;

    for (int k0 = 0; k0 < E; k0 += BK) {
        const float4 av = *(const float4*)(featp + k0);
        __syncthreads();                      // previous chunk fully consumed
        *(float4*)&A[lrow][lk] = av;
        __syncthreads();

        #pragma unroll
        for (int kg = 0; kg < BK; kg += 4) {
            float wr4[4], wi4[4], wp4[4];
            #pragma unroll
            for (int u = 0; u < 4; ++u) {
                const int k = k0 + kg + u;
                wr4[u] = Wr [k * Q + j];      // coalesced across lanes, L2-resident
                wi4[u] = Wi [k * Q + j];
                wp4[u] = Wp1[k * Q + j];
            }
            #pragma unroll
            for (int r = 0; r < RPT; ++r) {
                const float4 a = *(const float4*)&A[w * RPT + r][kg];  // wave-broadcast ds_read_b128
                accR[r] = fmaf(a.x, wr4[0], fmaf(a.y, wr4[1], fmaf(a.z, wr4[2], fmaf(a.w, wr4[3], accR[r]))));
                accI[r] = fmaf(a.x, wi4[0], fmaf(a.y, wi4[1], fmaf(a.z, wi4[2], fmaf(a.w, wi4[3], accI[r]))));
                accP[r] = fmaf(a.x, wp4[0], fmaf(a.y, wp4[1], fmaf(a.z, wp4[2], fmaf(a.w, wp4[3], accP[r]))));
            }
        }
    }

    // ---- activations; stage tanh(p1) for the 64x64 matvec ----
    const float bRv = br[j], bIv = bi[j], bPv = bp1[j];
    float rv[RPT], iv[RPT];
    #pragma unroll
    for (int r = 0; r < RPT; ++r) {
        rv[r] = tanhf(accR[r] + bRv);
        iv[r] = tanhf(accI[r] + bIv);
        T[w * RPT + r][j] = tanhf(accP[r] + bPv);
    }
    __syncthreads();

    // ---- phases = tanh(T @ W_p2 + b_p2) * pi ----
    float ph[RPT];
    {
        float s[RPT];
        const float bP2v = bp2[j];
        #pragma unroll
        for (int r = 0; r < RPT; ++r) s[r] = bP2v;
        #pragma unroll
        for (int k = 0; k < Q; k += 4) {
            const float w0 = Wp2[(k + 0) * Q + j];
            const float w1 = Wp2[(k + 1) * Q + j];
            const float w2 = Wp2[(k + 2) * Q + j];
            const float w3 = Wp2[(k + 3) * Q + j];
            #pragma unroll
            for (int r = 0; r < RPT; ++r) {
                const float4 t4 = *(const float4*)&T[w * RPT + r][k];
                s[r] = fmaf(t4.x, w0, fmaf(t4.y, w1, fmaf(t4.z, w2, fmaf(t4.w, w3, s[r]))));
            }
        }
        #pragma unroll
        for (int r = 0; r < RPT; ++r) ph[r] = tanhf(s[r]) * PI_F;
    }

    // ---- structured Hermitian operator epilogue ----
    const float pj    = op_p[j];
    const float sig   = 1.f / (1.f + expf(-pj));
    const float dcoef = sig - pj * pj;   // diag correction: replace p_j^2 term with sigmoid

    float* __restrict__ outR = out;
    float* __restrict__ outI = out +       nrows * Q;
    float* __restrict__ outP = out + 2LL * nrows * Q;

    #pragma unroll
    for (int r = 0; r < RPT; ++r) {
        float si, co;
        sincosf(ph[r], &si, &co);
        const float rp = rv[r] * co - iv[r] * si;
        const float ip = rv[r] * si + iv[r] * co;

        float n2 = rp * rp + ip * ip;
        #pragma unroll
        for (int off = 32; off >= 1; off >>= 1)
            n2 += __shfl_xor(n2, off);                 // wave-64 reduce
        const float inv = 1.f / sqrtf(n2 + 1e-12f);
        const float rn  = rp * inv;
        const float inn = ip * inv;

        float dRp = rn * pj, dIp = inn * pj, sR = rn, sI = inn;
        #pragma unroll
        for (int off = 32; off >= 1; off >>= 1) {
            dRp += __shfl_xor(dRp, off);
            dIp += __shfl_xor(dIp, off);
            sR  += __shfl_xor(sR,  off);
            sI  += __shfl_xor(sI,  off);
        }

        const long long row = row0 + (long long)(w * RPT + r);
        // out_r = (rn.p)p_j + rn_j(sig_j - p_j^2) - [(inn.p) - (sum inn) p_j]
        outR[row * Q + j] = dRp * pj + rn * dcoef - dIp + sI * pj;
        // out_i = [(rn.p) - (sum rn) p_j] + [(inn.p) p_j + inn_j(sig_j - p_j^2)]
        outI[row * Q + j] = dRp - sR * pj + inn * dcoef + dIp * pj;
        outP[row * Q + j] = ph[r];
    }
}

extern "C" void kernel_launch(void* const* d_in, const int* in_sizes, int n_in,
                              void* d_out, int out_size, void* d_ws, size_t ws_size,
                              hipStream_t stream) {
    const float* feat = (const float*)d_in[0];
    const float* Wr   = (const float*)d_in[1];
    const float* br   = (const float*)d_in[2];
    const float* Wi   = (const float*)d_in[3];
    const float* bi   = (const float*)d_in[4];
    const float* Wp1  = (const float*)d_in[5];
    const float* bp1  = (const float*)d_in[6];
    const float* Wp2  = (const float*)d_in[7];
    const float* bp2  = (const float*)d_in[8];
    const float* opp  = (const float*)d_in[9];

    const long long nrows = (long long)in_sizes[0] / E;   // 32*4096 = 131072
    const int blocks = (int)(nrows / MTILE);              // 2048

    hipLaunchKernelGGL(qi_fused, dim3(blocks), dim3(256), 0, stream,
                       feat, Wr, br, Wi, bi, Wp1, bp1, Wp2, bp2, opp,
                       (float*)d_out, nrows);
}

// Round 2
// 1118.641 us; speedup vs baseline: 2.5704x; 2.5704x over previous
//
#include <hip/hip_runtime.h>
#include <math.h>

#define PI_F 3.14159265358979323846f

constexpr int E = 512;    // feature dim
constexpr int Q = 64;     // quantum dim
constexpr int MTILE = 32; // rows per block
constexpr int BK = 32;    // K chunk staged in LDS
constexpr int RPT = 8;    // rows per wave (64 lanes = 64 output cols)
constexpr int APAD = 4;   // A row stride pad: kills 8-way ds_write conflict

// fast tanh via hardware exp2: (e^{2x}-1)/(e^{2x}+1), clamped to avoid inf/inf
__device__ __forceinline__ float tanh_fast(float x) {
    const float xc = fminf(fmaxf(x, -15.f), 15.f);
    const float e  = __expf(2.f * xc);
    return (e - 1.f) / (e + 1.f);
}

__global__ __launch_bounds__(256, 4)
void qi_fused(const float* __restrict__ feat,
              const float* __restrict__ Wr,  const float* __restrict__ br,
              const float* __restrict__ Wi,  const float* __restrict__ bi,
              const float* __restrict__ Wp1, const float* __restrict__ bp1,
              const float* __restrict__ Wp2, const float* __restrict__ bp2,
              const float* __restrict__ op_p,
              float* __restrict__ out, long long nrows)
{
    __shared__ float A[MTILE][BK + APAD];  // 4.5 KB feature chunk
    __shared__ float T[MTILE][Q + 4];      // 8.5 KB tanh(p1) staging

    const int tid = threadIdx.x;
    const int j   = tid & 63;          // output column (lane)
    const int w   = tid >> 6;          // wave id -> row group
    const long long row0 = (long long)blockIdx.x * MTILE;

    float accR[RPT], accI[RPT], accP[RPT];
    #pragma unroll
    for (int r = 0; r < RPT; ++r) { accR[r] = 0.f; accI[r] = 0.f; accP[r] = 0.f; }

    // A-tile loader: thread t loads float4 at (row = t/8, k = (t%8)*4) -> 32x32 chunk
    const int lrow = tid >> 3;
    const int lk   = (tid & 7) << 2;
    const float* featp = feat + (row0 + lrow) * (long long)E + lk;

    float4 av = *(const float4*)(featp);   // prefetch chunk 0

    for (int k0 = 0; k0 < E; k0 += BK) {
        __syncthreads();                   // previous chunk fully consumed
        *(float4*)&A[lrow][lk] = av;
        __syncthreads();
        if (k0 + BK < E) av = *(const float4*)(featp + k0 + BK);  // prefetch next

        #pragma unroll
        for (int kg = 0; kg < BK; kg += 4) {
            float wr4[4], wi4[4], wp4[4];
            #pragma unroll
            for (int u = 0; u < 4; ++u) {
                const int k = k0 + kg + u;
                wr4[u] = Wr [k * Q + j];   // coalesced across lanes, L1/L2-resident
                wi4[u] = Wi [k * Q + j];
                wp4[u] = Wp1[k * Q + j];
            }
            #pragma unroll
            for (int r = 0; r < RPT; ++r) {
                const float4 a = *(const float4*)&A[w * RPT + r][kg];  // broadcast read
                accR[r] = fmaf(a.x, wr4[0], fmaf(a.y, wr4[1], fmaf(a.z, wr4[2], fmaf(a.w, wr4[3], accR[r]))));
                accI[r] = fmaf(a.x, wi4[0], fmaf(a.y, wi4[1], fmaf(a.z, wi4[2], fmaf(a.w, wi4[3], accI[r]))));
                accP[r] = fmaf(a.x, wp4[0], fmaf(a.y, wp4[1], fmaf(a.z, wp4[2], fmaf(a.w, wp4[3], accP[r]))));
            }
        }
    }

    // ---- activations; stage tanh(p1) for the 64x64 matvec ----
    const float bRv = br[j], bIv = bi[j], bPv = bp1[j];
    float rv[RPT], iv[RPT];
    #pragma unroll
    for (int r = 0; r < RPT; ++r) {
        rv[r] = tanh_fast(accR[r] + bRv);
        iv[r] = tanh_fast(accI[r] + bIv);
        T[w * RPT + r][j] = tanh_fast(accP[r] + bPv);
    }
    __syncthreads();

    // ---- phases = tanh(T @ W_p2 + b_p2) * pi ----
    float ph[RPT];
    {
        float s[RPT];
        const float bP2v = bp2[j];
        #pragma unroll
        for (int r = 0; r < RPT; ++r) s[r] = bP2v;
        #pragma unroll
        for (int k = 0; k < Q; k += 4) {
            const float w0 = Wp2[(k + 0) * Q + j];
            const float w1 = Wp2[(k + 1) * Q + j];
            const float w2 = Wp2[(k + 2) * Q + j];
            const float w3 = Wp2[(k + 3) * Q + j];
            #pragma unroll
            for (int r = 0; r < RPT; ++r) {
                const float4 t4 = *(const float4*)&T[w * RPT + r][k];
                s[r] = fmaf(t4.x, w0, fmaf(t4.y, w1, fmaf(t4.z, w2, fmaf(t4.w, w3, s[r]))));
            }
        }
        #pragma unroll
        for (int r = 0; r < RPT; ++r) ph[r] = tanh_fast(s[r]) * PI_F;
    }

    // ---- structured Hermitian operator epilogue ----
    // R = p p^T with diag -> sigmoid(p):  (x@R)_j = (x.p) p_j + x_j (sig_j - p_j^2)
    // I[i,j] = p_i - p_j:                 (x@I)_j = (x.p) - (sum x) p_j
    const float pj    = op_p[j];
    const float sig   = 1.f / (1.f + __expf(-pj));
    const float dcoef = sig - pj * pj;

    float* __restrict__ outR = out;
    float* __restrict__ outI = out +       nrows * Q;
    float* __restrict__ outP = out + 2LL * nrows * Q;

    #pragma unroll
    for (int r = 0; r < RPT; ++r) {
        const float si = __sinf(ph[r]);
        const float co = __cosf(ph[r]);
        const float rp = rv[r] * co - iv[r] * si;
        const float ip = rv[r] * si + iv[r] * co;

        float n2 = rp * rp + ip * ip;
        #pragma unroll
        for (int off = 32; off >= 1; off >>= 1)
            n2 += __shfl_xor(n2, off);                 // wave-64 reduce
        const float inv = 1.f / sqrtf(n2 + 1e-12f);
        const float rn  = rp * inv;
        const float inn = ip * inv;

        float dRp = rn * pj, dIp = inn * pj, sR = rn, sI = inn;
        #pragma unroll
        for (int off = 32; off >= 1; off >>= 1) {
            dRp += __shfl_xor(dRp, off);
            dIp += __shfl_xor(dIp, off);
            sR  += __shfl_xor(sR,  off);
            sI  += __shfl_xor(sI,  off);
        }

        const long long row = row0 + (long long)(w * RPT + r);
        outR[row * Q + j] = dRp * pj + rn * dcoef - dIp + sI * pj;
        outI[row * Q + j] = dRp - sR * pj + inn * dcoef + dIp * pj;
        outP[row * Q + j] = ph[r];
    }
}

extern "C" void kernel_launch(void* const* d_in, const int* in_sizes, int n_in,
                              void* d_out, int out_size, void* d_ws, size_t ws_size,
                              hipStream_t stream) {
    const float* feat = (const float*)d_in[0];
    const float* Wr   = (const float*)d_in[1];
    const float* br   = (const float*)d_in[2];
    const float* Wi   = (const float*)d_in[3];
    const float* bi   = (const float*)d_in[4];
    const float* Wp1  = (const float*)d_in[5];
    const float* bp1  = (const float*)d_in[6];
    const float* Wp2  = (const float*)d_in[7];
    const float* bp2  = (const float*)d_in[8];
    const float* opp  = (const float*)d_in[9];

    const long long nrows = (long long)in_sizes[0] / E;   // 32*4096 = 131072
    const int blocks = (int)(nrows / MTILE);              // 4096

    hipLaunchKernelGGL(qi_fused, dim3(blocks), dim3(256), 0, stream,
                       feat, Wr, br, Wi, bi, Wp1, bp1, Wp2, bp2, opp,
                       (float*)d_out, nrows);
}

// Round 3
// 452.755 us; speedup vs baseline: 6.3507x; 2.4707x over previous
//
#include <hip/hip_runtime.h>
#include <math.h>

#define PI_F 3.14159265358979323846f

typedef __attribute__((ext_vector_type(8))) short  short8;   // 8 bf16 = 4 VGPRs (MFMA A/B frag)
typedef __attribute__((ext_vector_type(4))) float  floatx4;  // MFMA C/D frag

constexpr int E = 512;
constexpr int Q = 64;
constexpr int NCHUNK = E / 32;                 // 16 K-chunks for 16x16x32
constexpr int WS_B_ENTRIES = NCHUNK * 12 * 64; // 12288 16-B fragments (Wr|Wi|Wp1)
constexpr int WS_P2_OFF = WS_B_ENTRIES;        // then 2*4*64 = 512 fragments (Wp2)

__device__ __forceinline__ unsigned short bf16_rne(float x) {
    unsigned u = __float_as_uint(x);
    unsigned r = u + 0x7fffu + ((u >> 16) & 1u);
    return (unsigned short)(r >> 16);
}

// split fp32 -> hi bf16 + lo bf16 (residual); A_hi*B + A_lo*B recovers ~fp32 A precision
__device__ __forceinline__ void split_bf16_8(const float* v, short8& hi, short8& lo) {
    #pragma unroll
    for (int j = 0; j < 8; ++j) {
        unsigned u  = __float_as_uint(v[j]);
        unsigned rh = (u + 0x7fffu + ((u >> 16) & 1u)) & 0xffff0000u;
        hi[j] = (short)(rh >> 16);
        float res = v[j] - __uint_as_float(rh);
        lo[j] = (short)bf16_rne(res);
    }
}

__device__ __forceinline__ float tanh_fast(float x) {
    const float xc = fminf(fmaxf(x, -15.f), 15.f);
    const float e  = __expf(2.f * xc);
    return (e - 1.f) / (e + 1.f);
}

// ---- pack weights (fp32) into bf16 MFMA B-fragment order in d_ws ----
// B frag for 16x16x32: lane L holds B[k = kbase + (L>>4)*8 + j][n = tile*16 + (L&15)]
// frag index: (c*12 + mat*4 + tt)*64 + L  for the three E->Q mats; then Wp2 frags.
__global__ void prep_weights(const float* __restrict__ Wr, const float* __restrict__ Wi,
                             const float* __restrict__ Wp1, const float* __restrict__ Wp2,
                             short* __restrict__ ws)
{
    const int e = blockIdx.x * 256 + threadIdx.x;   // grid sized exactly
    const float* W;
    int kbase, n;
    if (e < WS_B_ENTRIES) {
        const int L = e & 63;
        const int f = e >> 6;          // 0..191
        const int tt = f & 3;
        const int g  = f >> 2;         // 0..47
        const int m  = g % 3, c = g / 3;
        W = (m == 0) ? Wr : (m == 1) ? Wi : Wp1;
        n     = tt * 16 + (L & 15);
        kbase = c * 32 + (L >> 4) * 8;
    } else {
        const int e2 = e - WS_B_ENTRIES;   // 0..511
        const int L  = e2 & 63;
        const int tt = (e2 >> 6) & 3;
        const int c2 = e2 >> 8;
        W = Wp2;
        n     = tt * 16 + (L & 15);
        kbase = c2 * 32 + (L >> 4) * 8;
    }
    short8 frag;
    #pragma unroll
    for (int j = 0; j < 8; ++j)
        frag[j] = (short)bf16_rne(W[(kbase + j) * Q + n]);
    *(short8*)(ws + (size_t)e * 8) = frag;
}

__global__ __launch_bounds__(256, 3)
void qi_mfma(const float* __restrict__ feat, const short* __restrict__ wsb,
             const float* __restrict__ br,  const float* __restrict__ bi,
             const float* __restrict__ bp1, const float* __restrict__ bp2,
             const float* __restrict__ op_p,
             float* __restrict__ out, long long nrows)
{
    __shared__ float Tp[4][16][68];   // per-wave tanh(p1) staging; stride 68 -> 2-way (free) conflicts

    const int tid = threadIdx.x;
    const int L   = tid & 63;
    const int w   = tid >> 6;
    const int l15 = L & 15;
    const int q4  = L >> 4;                       // quad id
    const long long rowBase = (long long)blockIdx.x * 64 + w * 16;

    // A gather: lane reads rows rowBase+l15, k = c*32 + q4*8 + [0..7]  (A[m=lane&15][k=quad*8+j])
    const float* aptr = feat + (rowBase + l15) * (long long)E + q4 * 8;
    const short8* wfrag = (const short8*)wsb;

    floatx4 acc[12];
    #pragma unroll
    for (int t = 0; t < 12; ++t) acc[t] = (floatx4){0.f, 0.f, 0.f, 0.f};

    for (int c = 0; c < NCHUNK; ++c) {
        float av[8];
        {
            const floatx4 a0 = *(const floatx4*)(aptr + c * 32);
            const floatx4 a1 = *(const floatx4*)(aptr + c * 32 + 4);
            #pragma unroll
            for (int j = 0; j < 4; ++j) { av[j] = a0[j]; av[4 + j] = a1[j]; }
        }
        short8 ah, al;
        split_bf16_8(av, ah, al);

        const size_t cb = (size_t)(c * 12) * 64 + L;
        #pragma unroll
        for (int mt = 0; mt < 12; ++mt) {
            const short8 bf = wfrag[cb + (size_t)mt * 64];
            acc[mt] = __builtin_amdgcn_mfma_f32_16x16x32_bf16(ah, bf, acc[mt], 0, 0, 0);
            acc[mt] = __builtin_amdgcn_mfma_f32_16x16x32_bf16(al, bf, acc[mt], 0, 0, 0);
        }
    }

    // ---- per-held-column constants (col = t*16 + l15) ----
    float brv[4], biv[4], bp1v[4], bp2v[4], pv[4], dcv[4];
    #pragma unroll
    for (int t = 0; t < 4; ++t) {
        const int colv = t * 16 + l15;
        brv[t] = br[colv]; biv[t] = bi[colv]; bp1v[t] = bp1[colv]; bp2v[t] = bp2[colv];
        const float p = op_p[colv];
        pv[t]  = p;
        dcv[t] = 1.f / (1.f + __expf(-p)) - p * p;   // sigmoid(p) - p^2 (diag correction)
    }

    // ---- activations; stage tanh(p1) for the Wp2 MFMA (C-layout -> LDS) ----
    float rv[4][4], iv[4][4];
    #pragma unroll
    for (int t = 0; t < 4; ++t)
        #pragma unroll
        for (int g = 0; g < 4; ++g) {
            rv[t][g] = tanh_fast(acc[t][g]     + brv[t]);
            iv[t][g] = tanh_fast(acc[4 + t][g] + biv[t]);
            Tp[w][q4 * 4 + g][t * 16 + l15] = tanh_fast(acc[8 + t][g] + bp1v[t]);
        }
    __syncthreads();

    // ---- phase layer 2: P2 = tanh(Tp) @ Wp2 via split-A MFMA over K=64 ----
    floatx4 accp2[4];
    #pragma unroll
    for (int t = 0; t < 4; ++t) accp2[t] = (floatx4){0.f, 0.f, 0.f, 0.f};
    #pragma unroll
    for (int c2 = 0; c2 < 2; ++c2) {
        float tv[8];
        {
            const floatx4 t0 = *(const floatx4*)&Tp[w][l15][c2 * 32 + q4 * 8];
            const floatx4 t1 = *(const floatx4*)&Tp[w][l15][c2 * 32 + q4 * 8 + 4];
            #pragma unroll
            for (int j = 0; j < 4; ++j) { tv[j] = t0[j]; tv[4 + j] = t1[j]; }
        }
        short8 th, tl;
        split_bf16_8(tv, th, tl);
        #pragma unroll
        for (int tt = 0; tt < 4; ++tt) {
            const short8 bf = wfrag[(size_t)(WS_P2_OFF + (c2 * 4 + tt) * 64 + L)];
            accp2[tt] = __builtin_amdgcn_mfma_f32_16x16x32_bf16(th, bf, accp2[tt], 0, 0, 0);
            accp2[tt] = __builtin_amdgcn_mfma_f32_16x16x32_bf16(tl, bf, accp2[tt], 0, 0, 0);
        }
    }

    float* __restrict__ outR = out;
    float* __restrict__ outI = out +       nrows * Q;
    float* __restrict__ outP = out + 2LL * nrows * Q;

    // ---- phases, rotation; store phases now to free registers ----
    float rp[4][4], ip[4][4];
    #pragma unroll
    for (int t = 0; t < 4; ++t)
        #pragma unroll
        for (int g = 0; g < 4; ++g) {
            const float ph = tanh_fast(accp2[t][g] + bp2v[t]) * PI_F;
            const long long row = rowBase + q4 * 4 + g;
            outP[row * Q + t * 16 + l15] = ph;
            const float si = __sinf(ph), co = __cosf(ph);
            rp[t][g] = rv[t][g] * co - iv[t][g] * si;
            ip[t][g] = rv[t][g] * si + iv[t][g] * co;
        }

    // ---- per-row normalization + structured Hermitian operator ----
    // row of lane = q4*4+g; its 64 cols live in this quad's 16 lanes x 4 tiles
    #pragma unroll
    for (int g = 0; g < 4; ++g) {
        float n2 = 0.f;
        #pragma unroll
        for (int t = 0; t < 4; ++t) n2 += rp[t][g] * rp[t][g] + ip[t][g] * ip[t][g];
        #pragma unroll
        for (int off = 1; off <= 8; off <<= 1) n2 += __shfl_xor(n2, off);  // intra-quad reduce
        const float inv = 1.f / sqrtf(n2 + 1e-12f);

        float dR = 0.f, dI = 0.f, sR = 0.f, sI = 0.f;
        #pragma unroll
        for (int t = 0; t < 4; ++t) {
            rp[t][g] *= inv; ip[t][g] *= inv;        // rn, inn
            dR += rp[t][g] * pv[t];  dI += ip[t][g] * pv[t];
            sR += rp[t][g];          sI += ip[t][g];
        }
        #pragma unroll
        for (int off = 1; off <= 8; off <<= 1) {
            dR += __shfl_xor(dR, off); dI += __shfl_xor(dI, off);
            sR += __shfl_xor(sR, off); sI += __shfl_xor(sI, off);
        }

        const long long row = rowBase + q4 * 4 + g;
        #pragma unroll
        for (int t = 0; t < 4; ++t) {
            const long long o = row * Q + t * 16 + l15;
            // (x@R)_j = (x.p)p_j + x_j(sig_j - p_j^2);  (x@I)_j = (x.p) - (sum x) p_j
            outR[o] = dR * pv[t] + rp[t][g] * dcv[t] - dI + sI * pv[t];
            outI[o] = dR - sR * pv[t] + ip[t][g] * dcv[t] + dI * pv[t];
        }
    }
}

extern "C" void kernel_launch(void* const* d_in, const int* in_sizes, int n_in,
                              void* d_out, int out_size, void* d_ws, size_t ws_size,
                              hipStream_t stream) {
    const float* feat = (const float*)d_in[0];
    const float* Wr   = (const float*)d_in[1];
    const float* br   = (const float*)d_in[2];
    const float* Wi   = (const float*)d_in[3];
    const float* bi   = (const float*)d_in[4];
    const float* Wp1  = (const float*)d_in[5];
    const float* bp1  = (const float*)d_in[6];
    const float* Wp2  = (const float*)d_in[7];
    const float* bp2  = (const float*)d_in[8];
    const float* opp  = (const float*)d_in[9];

    short* ws = (short*)d_ws;   // needs (12288+512)*16 = 200 KB

    const long long nrows = (long long)in_sizes[0] / E;   // 131072
    const int blocks = (int)(nrows / 64);                 // 2048

    hipLaunchKernelGGL(prep_weights, dim3((WS_B_ENTRIES + 512) / 256), dim3(256), 0, stream,
                       Wr, Wi, Wp1, Wp2, ws);
    hipLaunchKernelGGL(qi_mfma, dim3(blocks), dim3(256), 0, stream,
                       feat, ws, br, bi, bp1, bp2, opp, (float*)d_out, nrows);
}